// Round 1
// baseline (564.072 us; speedup 1.0000x reference)
//
#include <hip/hip_runtime.h>

#define NN 50000
#define NE 800000

constexpr int SCAN_CHUNK = 1024;
constexpr int NBLK_SCAN = (NN + SCAN_CHUNK - 1) / SCAN_CHUNK; // 49

// ---------------- CSR build ----------------

__global__ void hist_k(const int* __restrict__ dst, int* __restrict__ deg, int E) {
    int e = blockIdx.x * blockDim.x + threadIdx.x;
    if (e < E) atomicAdd(&deg[dst[e]], 1);
}

__global__ void scanA_k(const int* __restrict__ deg, int* __restrict__ rp,
                        int* __restrict__ partials, int n) {
    __shared__ int sm[256];
    int tid = threadIdx.x;
    int base = blockIdx.x * SCAN_CHUNK + tid * 4;
    int v0 = (base + 0 < n) ? deg[base + 0] : 0;
    int v1 = (base + 1 < n) ? deg[base + 1] : 0;
    int v2 = (base + 2 < n) ? deg[base + 2] : 0;
    int v3 = (base + 3 < n) ? deg[base + 3] : 0;
    int s = v0 + v1 + v2 + v3;
    sm[tid] = s;
    __syncthreads();
    for (int off = 1; off < 256; off <<= 1) {
        int t = (tid >= off) ? sm[tid - off] : 0;
        __syncthreads();
        sm[tid] += t;
        __syncthreads();
    }
    int excl = sm[tid] - s;  // exclusive prefix of this thread's 4 elems
    if (base + 0 < n) rp[base + 0] = excl;
    if (base + 1 < n) rp[base + 1] = excl + v0;
    if (base + 2 < n) rp[base + 2] = excl + v0 + v1;
    if (base + 3 < n) rp[base + 3] = excl + v0 + v1 + v2;
    if (tid == 255) partials[blockIdx.x] = sm[255];
}

__global__ void scanB_k(int* __restrict__ partials, int nblk) {
    if (threadIdx.x == 0 && blockIdx.x == 0) {
        int run = 0;
        for (int b = 0; b < nblk; ++b) {
            int v = partials[b];
            partials[b] = run;
            run += v;
        }
    }
}

__global__ void scanC_k(int* __restrict__ rp, const int* __restrict__ partials,
                        int* __restrict__ cursor, int n, int E) {
    int i = blockIdx.x * blockDim.x + threadIdx.x;
    if (i < n) {
        int v = rp[i] + partials[i >> 10];
        rp[i] = v;
        cursor[i] = v;
    }
    if (i == 0) rp[n] = E;
}

__global__ void scatter_k(const int* __restrict__ src, const int* __restrict__ dst,
                          const float* __restrict__ w, int* __restrict__ cursor,
                          int* __restrict__ ssrc, float* __restrict__ sw, int E) {
    int e = blockIdx.x * blockDim.x + threadIdx.x;
    if (e < E) {
        int d = dst[e];
        int p = atomicAdd(&cursor[d], 1);
        ssrc[p] = src[e];
        sw[p]  = w[e];
    }
}

// ---------------- SpMM (gather, one wave per node) ----------------
// out[d][:] = sum_{e: dst=d} w_e * feat[src_e][:]   (F = 64 or 128)

template <int F, bool DO_WSUM>
__global__ void spmm_k(const float* __restrict__ feat, const int* __restrict__ rp,
                       const int* __restrict__ ssrc, const float* __restrict__ sw,
                       float* __restrict__ out, float* __restrict__ wsum, int n) {
    int gt   = blockIdx.x * blockDim.x + threadIdx.x;
    int wid  = gt >> 6;          // node
    int lane = threadIdx.x & 63;
    if (wid >= n) return;
    int beg = rp[wid], end = rp[wid + 1];
    constexpr int J = F / 64;
    float acc[J];
#pragma unroll
    for (int j = 0; j < J; ++j) acc[j] = 0.f;
    float wacc = 0.f;
    for (int p = beg; p < end; ++p) {
        int s    = ssrc[p];
        float wt = sw[p];
        wacc += wt;
        const float* fp = feat + (size_t)s * F + lane;
#pragma unroll
        for (int j = 0; j < J; ++j) acc[j] = fmaf(wt, fp[64 * j], acc[j]);
    }
    float* op = out + (size_t)wid * F + lane;
#pragma unroll
    for (int j = 0; j < J; ++j) op[64 * j] = acc[j];
    if (DO_WSUM && lane == 0) wsum[wid] = wacc;
}

// ---------------- GEMM: C[N x 128tile] = relu( A' @ B ) ----------------
// A' = A (FUSEA=false)  or  A*scaleA[k] + wsum[r]*biasA[k] (FUSEA=true)
// Block: 64 rows x 128 cols, 256 threads, 8x4 register tile per thread.

template <int K, int BK, bool FUSEA>
__launch_bounds__(256)
__global__ void gemm_k(const float* __restrict__ A, const float* __restrict__ B,
                       float* __restrict__ C, int n, int ldb, int ldc,
                       const float* __restrict__ scaleA, const float* __restrict__ biasA,
                       const float* __restrict__ wsumA) {
    __shared__ float As[64 * K];
    __shared__ float Bs[BK][128];
    int tid = threadIdx.x;
    int r0  = blockIdx.x * 64;
    int c0  = blockIdx.y * 128;

    // Stage As: linear copy of 64 rows x K (A rows are exactly K wide).
    {
        const float4* A4 = reinterpret_cast<const float4*>(A + (size_t)r0 * K);
#pragma unroll
        for (int it = 0; it < (16 * K) / 256; ++it) {
            int idx  = it * 256 + tid;     // float4 index
            float4 v = A4[idx];            // rows past n read scratch slack: never stored
            if (FUSEA) {
                int k = (idx * 4) & (K - 1);
                int r = (idx * 4) / K;
                float4 sc = *reinterpret_cast<const float4*>(scaleA + k);
                float4 bi = *reinterpret_cast<const float4*>(biasA + k);
                float ws  = wsumA[r0 + r];
                v.x = fmaf(v.x, sc.x, ws * bi.x);
                v.y = fmaf(v.y, sc.y, ws * bi.y);
                v.z = fmaf(v.z, sc.z, ws * bi.z);
                v.w = fmaf(v.w, sc.w, ws * bi.w);
            }
            reinterpret_cast<float4*>(As)[idx] = v;
        }
    }

    float acc[8][4];
#pragma unroll
    for (int i = 0; i < 8; ++i)
#pragma unroll
        for (int j = 0; j < 4; ++j) acc[i][j] = 0.f;

    int g  = tid >> 5;   // 0..7 row group
    int tc = tid & 31;   // col group (4 cols each)

    for (int kb = 0; kb < K; kb += BK) {
        // Stage Bs chunk [BK][128]
#pragma unroll
        for (int it = 0; it < (BK * 32) / 256; ++it) {
            int idx = it * 256 + tid;
            int kk  = idx >> 5;
            int cf  = idx & 31;
            reinterpret_cast<float4*>(&Bs[kk][0])[cf] =
                reinterpret_cast<const float4*>(B + (size_t)(kb + kk) * ldb + c0)[cf];
        }
        __syncthreads();
#pragma unroll
        for (int k4 = 0; k4 < BK; k4 += 4) {
            float4 a4[8];
#pragma unroll
            for (int i = 0; i < 8; ++i)
                a4[i] = *reinterpret_cast<const float4*>(&As[(g * 8 + i) * K + kb + k4]);
#pragma unroll
            for (int kk = 0; kk < 4; ++kk) {
                float4 b4 = *reinterpret_cast<const float4*>(&Bs[k4 + kk][tc * 4]);
#pragma unroll
                for (int i = 0; i < 8; ++i) {
                    float a = (kk == 0) ? a4[i].x : (kk == 1) ? a4[i].y
                            : (kk == 2) ? a4[i].z : a4[i].w;
                    acc[i][0] = fmaf(a, b4.x, acc[i][0]);
                    acc[i][1] = fmaf(a, b4.y, acc[i][1]);
                    acc[i][2] = fmaf(a, b4.z, acc[i][2]);
                    acc[i][3] = fmaf(a, b4.w, acc[i][3]);
                }
            }
        }
        __syncthreads();
    }

    // Epilogue: relu + store
#pragma unroll
    for (int i = 0; i < 8; ++i) {
        int r = r0 + g * 8 + i;
        if (r < n) {
            float4 o;
            o.x = fmaxf(acc[i][0], 0.f);
            o.y = fmaxf(acc[i][1], 0.f);
            o.z = fmaxf(acc[i][2], 0.f);
            o.w = fmaxf(acc[i][3], 0.f);
            *reinterpret_cast<float4*>(C + (size_t)r * ldc + c0 + tc * 4) = o;
        }
    }
}

// ---------------- BatchNorm ----------------

template <int F>
__global__ void bn_stats_k(const float* __restrict__ x, float* __restrict__ sums,
                           float* __restrict__ sqs, int n) {
    constexpr int RSTEP = 256 / F;
    int col = threadIdx.x & (F - 1);
    int rg  = threadIdx.x / F;
    float s = 0.f, q = 0.f;
    for (int r = blockIdx.x * RSTEP + rg; r < n; r += gridDim.x * RSTEP) {
        float v = x[(size_t)r * F + col];
        s += v;
        q += v * v;
    }
    atomicAdd(&sums[col], s);
    atomicAdd(&sqs[col], q);
}

template <int F>
__global__ void bn_fin_k(const float* __restrict__ sums, const float* __restrict__ sqs,
                         const float* __restrict__ gamma, const float* __restrict__ beta,
                         float* __restrict__ scale, float* __restrict__ bias, float inv_n) {
    int c = threadIdx.x;
    if (c < F) {
        float m  = sums[c] * inv_n;
        float v  = sqs[c] * inv_n - m * m;
        float rs = rsqrtf(v + 1e-5f);
        float sc = gamma[c] * rs;
        scale[c] = sc;
        bias[c]  = beta[c] - m * sc;
    }
}

__global__ void norm_out_k(float* __restrict__ out, const float* __restrict__ scale,
                           const float* __restrict__ bias, int n4) {
    int i = blockIdx.x * blockDim.x + threadIdx.x;
    int stride = gridDim.x * blockDim.x;
    for (; i < n4; i += stride) {
        float4 v = reinterpret_cast<float4*>(out)[i];
        int c = (i * 4) & 255;
        float4 sc = *reinterpret_cast<const float4*>(scale + c);
        float4 bi = *reinterpret_cast<const float4*>(bias + c);
        v.x = fmaf(v.x, sc.x, bi.x);
        v.y = fmaf(v.y, sc.y, bi.y);
        v.z = fmaf(v.z, sc.z, bi.z);
        v.w = fmaf(v.w, sc.w, bi.w);
        reinterpret_cast<float4*>(out)[i] = v;
    }
}

// ---------------- launch ----------------

extern "C" void kernel_launch(void* const* d_in, const int* in_sizes, int n_in,
                              void* d_out, int out_size, void* d_ws, size_t ws_size,
                              hipStream_t stream) {
    const float* y      = (const float*)d_in[0];
    const int*   esrc   = (const int*)d_in[1];
    const int*   edst   = (const int*)d_in[2];
    const float* ew     = (const float*)d_in[3];
    const float* W1     = (const float*)d_in[4];
    const float* gamma1 = (const float*)d_in[5];
    const float* beta1  = (const float*)d_in[6];
    const float* W2     = (const float*)d_in[7];
    const float* gamma2 = (const float*)d_in[8];
    const float* beta2  = (const float*)d_in[9];
    float* out = (float*)d_out;

    char* ws = (char*)d_ws;
    size_t off = 0;
    auto alloc = [&](size_t bytes) -> void* {
        void* p = (void*)(ws + off);
        off += (bytes + 255) & ~(size_t)255;
        return p;
    };
    float* t1      = (float*)alloc((size_t)NN * 64 * 4);   // spmm(y)
    float* h1      = (float*)alloc((size_t)NN * 128 * 4);  // relu(t1@W1)
    float* t2      = (float*)alloc((size_t)NN * 128 * 4);  // spmm(h1)
    int*   rp      = (int*)alloc((NN + 1) * 4);
    int*   cursor  = (int*)alloc(NN * 4);
    int*   deg     = (int*)alloc(NN * 4);
    int*   ssrc    = (int*)alloc((size_t)NE * 4);
    float* sw      = (float*)alloc((size_t)NE * 4);
    float* wsum    = (float*)alloc(NN * 4);
    int*   partials= (int*)alloc(NBLK_SCAN * 4);
    float* stats   = (float*)alloc(768 * 4);  // colsum1[128] colsq1[128] colsum2[256] colsq2[256]
    float* colsum1 = stats;
    float* colsq1  = stats + 128;
    float* colsum2 = stats + 256;
    float* colsq2  = stats + 512;
    float* scale1  = (float*)alloc(128 * 4);
    float* bias1   = (float*)alloc(128 * 4);
    float* scale2  = (float*)alloc(256 * 4);
    float* bias2   = (float*)alloc(256 * 4);
    (void)alloc(64 * 1024);  // slack for harmless over-reads past last array

    hipMemsetAsync(deg, 0, NN * 4, stream);
    hipMemsetAsync(stats, 0, 768 * 4, stream);

    // CSR build (by dst)
    hist_k<<<(NE + 255) / 256, 256, 0, stream>>>(edst, deg, NE);
    scanA_k<<<NBLK_SCAN, 256, 0, stream>>>(deg, rp, partials, NN);
    scanB_k<<<1, 64, 0, stream>>>(partials, NBLK_SCAN);
    scanC_k<<<(NN + 255) / 256, 256, 0, stream>>>(rp, partials, cursor, NN, NE);
    scatter_k<<<(NE + 255) / 256, 256, 0, stream>>>(esrc, edst, ew, cursor, ssrc, sw, NE);

    // Layer 1: t1 = spmm(y); h1 = relu(t1 @ W1); BN1 -> scale1/bias1
    spmm_k<64, true><<<(NN + 3) / 4, 256, 0, stream>>>(y, rp, ssrc, sw, t1, wsum, NN);
    gemm_k<64, 64, false><<<dim3((NN + 63) / 64, 1), 256, 0, stream>>>(
        t1, W1, h1, NN, 128, 128, nullptr, nullptr, nullptr);
    bn_stats_k<128><<<512, 256, 0, stream>>>(h1, colsum1, colsq1, NN);
    bn_fin_k<128><<<1, 128, 0, stream>>>(colsum1, colsq1, gamma1, beta1, scale1, bias1,
                                         1.0f / NN);

    // Layer 2: t2 = spmm(h1); out = relu((t2*scale1 + wsum*bias1) @ W2); BN2 in-place
    spmm_k<128, false><<<(NN + 1) / 2, 256, 0, stream>>>(h1, rp, ssrc, sw, t2, nullptr, NN);
    gemm_k<128, 32, true><<<dim3((NN + 63) / 64, 2), 256, 0, stream>>>(
        t2, W2, out, NN, 256, 256, scale1, bias1, wsum);
    bn_stats_k<256><<<512, 256, 0, stream>>>(out, colsum2, colsq2, NN);
    bn_fin_k<256><<<1, 256, 0, stream>>>(colsum2, colsq2, gamma2, beta2, scale2, bias2,
                                         1.0f / NN);
    norm_out_k<<<2048, 256, 0, stream>>>(out, scale2, bias2, NN * 256 / 4);
}

// Round 2
// 376.061 us; speedup vs baseline: 1.4999x; 1.4999x over previous
//
#include <hip/hip_runtime.h>

#define NN 50000
#define NE 800000

typedef unsigned short ushort_t;
typedef __attribute__((ext_vector_type(8))) short short8;
typedef __attribute__((ext_vector_type(4))) float f32x4;

constexpr int SCAN_CHUNK = 1024;
constexpr int NBLK_SCAN = (NN + SCAN_CHUNK - 1) / SCAN_CHUNK; // 49

// ---------------- bf16 helpers (bit-exact, RNE) ----------------
__device__ __forceinline__ float bf2f(ushort_t u) {
    union { unsigned int i; float f; } v;
    v.i = ((unsigned int)u) << 16;
    return v.f;
}
__device__ __forceinline__ ushort_t f2bf(float f) {
    union { float f; unsigned int u; } v;
    v.f = f;
    unsigned int r = (v.u + 0x7fffu + ((v.u >> 16) & 1u)) >> 16;
    return (ushort_t)r;
}

// ---------------- CSR build ----------------

__global__ void hist_k(const int* __restrict__ dst, int* __restrict__ deg, int E) {
    int e = blockIdx.x * blockDim.x + threadIdx.x;
    if (e < E) atomicAdd(&deg[dst[e]], 1);
}

__global__ void scanA_k(const int* __restrict__ deg, int* __restrict__ rp,
                        int* __restrict__ partials, int n) {
    __shared__ int sm[256];
    int tid = threadIdx.x;
    int base = blockIdx.x * SCAN_CHUNK + tid * 4;
    int v0 = (base + 0 < n) ? deg[base + 0] : 0;
    int v1 = (base + 1 < n) ? deg[base + 1] : 0;
    int v2 = (base + 2 < n) ? deg[base + 2] : 0;
    int v3 = (base + 3 < n) ? deg[base + 3] : 0;
    int s = v0 + v1 + v2 + v3;
    sm[tid] = s;
    __syncthreads();
    for (int off = 1; off < 256; off <<= 1) {
        int t = (tid >= off) ? sm[tid - off] : 0;
        __syncthreads();
        sm[tid] += t;
        __syncthreads();
    }
    int excl = sm[tid] - s;
    if (base + 0 < n) rp[base + 0] = excl;
    if (base + 1 < n) rp[base + 1] = excl + v0;
    if (base + 2 < n) rp[base + 2] = excl + v0 + v1;
    if (base + 3 < n) rp[base + 3] = excl + v0 + v1 + v2;
    if (tid == 255) partials[blockIdx.x] = sm[255];
}

__global__ void scanB_k(int* __restrict__ partials, int nblk) {
    if (threadIdx.x == 0 && blockIdx.x == 0) {
        int run = 0;
        for (int b = 0; b < nblk; ++b) {
            int v = partials[b];
            partials[b] = run;
            run += v;
        }
    }
}

__global__ void scanC_k(int* __restrict__ rp, const int* __restrict__ partials,
                        int* __restrict__ cursor, int n, int E) {
    int i = blockIdx.x * blockDim.x + threadIdx.x;
    if (i < n) {
        int v = rp[i] + partials[i >> 10];
        rp[i] = v;
        cursor[i] = v;
    }
    if (i == 0) rp[n] = E;
}

__global__ void scatter_k(const int* __restrict__ src, const int* __restrict__ dst,
                          const float* __restrict__ w, int* __restrict__ cursor,
                          int* __restrict__ ssrc, float* __restrict__ sw, int E) {
    int e = blockIdx.x * blockDim.x + threadIdx.x;
    if (e < E) {
        int d = dst[e];
        int p = atomicAdd(&cursor[d], 1);
        ssrc[p] = src[e];
        sw[p]  = w[e];
    }
}

// ---------------- conversions ----------------

__global__ void cvt_y_k(const float* __restrict__ in, ushort_t* __restrict__ out, int n4) {
    int i = blockIdx.x * blockDim.x + threadIdx.x;
    if (i < n4) {
        float4 v = reinterpret_cast<const float4*>(in)[i];
        ushort4 o;
        o.x = f2bf(v.x); o.y = f2bf(v.y); o.z = f2bf(v.z); o.w = f2bf(v.w);
        reinterpret_cast<ushort4*>(out)[i] = o;
    }
}

// WT[c][k] = bf( W[k][c] ),  W is [Kd x Nd] row-major
__global__ void cvt_wt_k(const float* __restrict__ W, ushort_t* __restrict__ WT,
                         int Kd, int Nd) {
    int i = blockIdx.x * blockDim.x + threadIdx.x;
    if (i < Kd * Nd) {
        int c = i / Kd;
        int k = i - c * Kd;
        WT[i] = f2bf(W[k * Nd + c]);
    }
}

// ---------------- SpMM (bf16 gather, one wave per node) ----------------

__global__ void spmm1_k(const ushort_t* __restrict__ yb, const int* __restrict__ rp,
                        const int* __restrict__ ssrc, const float* __restrict__ sw,
                        ushort_t* __restrict__ t1, int n) {
    int wid  = (blockIdx.x * blockDim.x + threadIdx.x) >> 6;
    int lane = threadIdx.x & 63;
    if (wid >= n) return;
    int beg = rp[wid], end = rp[wid + 1];
    float acc = 0.f;
    for (int p = beg; p < end; ++p) {
        int s    = ssrc[p];
        float wt = sw[p];
        acc = fmaf(wt, bf2f(yb[(size_t)s * 64 + lane]), acc);
    }
    t1[(size_t)wid * 64 + lane] = f2bf(acc);
}

// gather h1 (bf16, 128 cols, 2 per lane), fold BN1: a2 = acc*scale1 + wsum*bias1
__global__ void spmm2_k(const ushort_t* __restrict__ h1, const int* __restrict__ rp,
                        const int* __restrict__ ssrc, const float* __restrict__ sw,
                        const float* __restrict__ scale1, const float* __restrict__ bias1,
                        ushort_t* __restrict__ a2, int n) {
    int wid  = (blockIdx.x * blockDim.x + threadIdx.x) >> 6;
    int lane = threadIdx.x & 63;
    if (wid >= n) return;
    int beg = rp[wid], end = rp[wid + 1];
    float a0 = 0.f, a1 = 0.f, wacc = 0.f;
    for (int p = beg; p < end; ++p) {
        int s    = ssrc[p];
        float wt = sw[p];
        wacc += wt;
        unsigned int u = *reinterpret_cast<const unsigned int*>(h1 + (size_t)s * 128 + lane * 2);
        a0 = fmaf(wt, bf2f((ushort_t)(u & 0xffffu)), a0);
        a1 = fmaf(wt, bf2f((ushort_t)(u >> 16)), a1);
    }
    float2 sc = *reinterpret_cast<const float2*>(scale1 + lane * 2);
    float2 bi = *reinterpret_cast<const float2*>(bias1 + lane * 2);
    unsigned int o = (unsigned int)f2bf(fmaf(a0, sc.x, wacc * bi.x))
                   | ((unsigned int)f2bf(fmaf(a1, sc.y, wacc * bi.y)) << 16);
    *reinterpret_cast<unsigned int*>(a2 + (size_t)wid * 128 + lane * 2) = o;
}

// ---------------- MFMA GEMM:  C[n x N] = relu( A[n x K](bf16) @ BT[N x K](bf16)^T ) ----
// Block: 256 thr = 4 waves (2x2), tile 64 rows x 128 cols. A staged in LDS with
// XOR swizzle (byte ^= (row&7)<<4) to break the stride-K2 bank conflict on
// ds_read_b128 (guide §6 G4). B fragments preloaded to registers from global (L2-hot).
// Fragment layout (16x16x32): A: row=lane&15, k=(lane>>4)*8+j (16B contiguous);
// B: col=lane&15, same k run; D: col=lane&15, row=(lane>>4)*4+reg.

template <int K, bool OUT_BF16>
__launch_bounds__(256)
__global__ void mgemm_k(const ushort_t* __restrict__ A, const ushort_t* __restrict__ BT,
                        void* __restrict__ Cout, int n, int N) {
    constexpr int K2 = K * 2;            // row bytes
    __shared__ char As[64 * K2];
    int tid = threadIdx.x;
    int r0  = blockIdx.x * 64;
    int c0  = blockIdx.y * 128;

    // Stage A-tile (rows past n read workspace slack; never stored)
    {
        const char* Ab = (const char*)(A + (size_t)r0 * K);
#pragma unroll
        for (int it = 0; it < (64 * K2) / 4096; ++it) {
            int p   = (it * 256 + tid) * 16;
            int row = p / K2;
            int cb  = p - row * K2;
            short8 v = *reinterpret_cast<const short8*>(Ab + p);
            *reinterpret_cast<short8*>(As + row * K2 + (cb ^ ((row & 7) << 4))) = v;
        }
    }

    int lane = tid & 63;
    int w    = tid >> 6;
    int wm0  = (w >> 1) * 32;
    int wn0  = (w & 1) * 64;
    int kg   = lane >> 4;
    int lr   = lane & 15;

    // Preload all B fragments (reused by 2 M-frags each; hides latency under staging)
    short8 bfrag[K / 32][4];
#pragma unroll
    for (int fn = 0; fn < 4; ++fn) {
        const ushort_t* bp = BT + (size_t)(c0 + wn0 + fn * 16 + lr) * K + kg * 8;
#pragma unroll
        for (int ks = 0; ks < K / 32; ++ks)
            bfrag[ks][fn] = *reinterpret_cast<const short8*>(bp + ks * 32);
    }

    __syncthreads();

    f32x4 acc[2][4];
#pragma unroll
    for (int i = 0; i < 2; ++i)
#pragma unroll
        for (int j = 0; j < 4; ++j) acc[i][j] = f32x4{0.f, 0.f, 0.f, 0.f};

#pragma unroll
    for (int ks = 0; ks < K / 32; ++ks) {
        int boff = ks * 64 + kg * 16;
        int row0 = wm0 + lr;
        int row1 = wm0 + 16 + lr;
        short8 a0 = *reinterpret_cast<const short8*>(As + row0 * K2 + (boff ^ ((row0 & 7) << 4)));
        short8 a1 = *reinterpret_cast<const short8*>(As + row1 * K2 + (boff ^ ((row1 & 7) << 4)));
#pragma unroll
        for (int fn = 0; fn < 4; ++fn) {
            acc[0][fn] = __builtin_amdgcn_mfma_f32_16x16x32_bf16(a0, bfrag[ks][fn], acc[0][fn], 0, 0, 0);
            acc[1][fn] = __builtin_amdgcn_mfma_f32_16x16x32_bf16(a1, bfrag[ks][fn], acc[1][fn], 0, 0, 0);
        }
    }

    // Epilogue: relu + store (bf16 or f32)
#pragma unroll
    for (int fm = 0; fm < 2; ++fm) {
        int rowb = r0 + wm0 + fm * 16 + kg * 4;
#pragma unroll
        for (int i = 0; i < 4; ++i) {
            int r = rowb + i;
            if (r < n) {
#pragma unroll
                for (int fn = 0; fn < 4; ++fn) {
                    float v = fmaxf(acc[fm][fn][i], 0.f);
                    int c = c0 + wn0 + fn * 16 + lr;
                    if constexpr (OUT_BF16)
                        ((ushort_t*)Cout)[(size_t)r * N + c] = f2bf(v);
                    else
                        ((float*)Cout)[(size_t)r * N + c] = v;
                }
            }
        }
    }
}

// ---------------- BatchNorm stats ----------------

// h1 bf16 [n x 128]: 2 cols/thread, 4-row groups, LDS pre-reduce, 4 atomics/col-pair/block
__global__ void stats1_k(const ushort_t* __restrict__ x, float* __restrict__ sums,
                         float* __restrict__ sqs, int n) {
    __shared__ float red[256][4];
    int tid = threadIdx.x;
    int cp  = tid & 63;   // col pair -> cols 2cp, 2cp+1
    int rg  = tid >> 6;   // 0..3
    float s0 = 0.f, q0 = 0.f, s1 = 0.f, q1 = 0.f;
    for (int r = blockIdx.x * 4 + rg; r < n; r += gridDim.x * 4) {
        unsigned int u = *reinterpret_cast<const unsigned int*>(x + (size_t)r * 128 + cp * 2);
        float v0 = bf2f((ushort_t)(u & 0xffffu));
        float v1 = bf2f((ushort_t)(u >> 16));
        s0 += v0; q0 += v0 * v0; s1 += v1; q1 += v1 * v1;
    }
    red[tid][0] = s0; red[tid][1] = q0; red[tid][2] = s1; red[tid][3] = q1;
    __syncthreads();
    if (tid < 64) {
        float a0 = 0.f, a1 = 0.f, a2 = 0.f, a3 = 0.f;
#pragma unroll
        for (int g = 0; g < 4; ++g) {
            a0 += red[g * 64 + tid][0]; a1 += red[g * 64 + tid][1];
            a2 += red[g * 64 + tid][2]; a3 += red[g * 64 + tid][3];
        }
        atomicAdd(&sums[tid * 2 + 0], a0);
        atomicAdd(&sqs [tid * 2 + 0], a1);
        atomicAdd(&sums[tid * 2 + 1], a2);
        atomicAdd(&sqs [tid * 2 + 1], a3);
    }
}

// out fp32 [n x 256]: 2 cols/thread, 2-row groups, LDS pre-reduce
__global__ void stats2_k(const float* __restrict__ x, float* __restrict__ sums,
                         float* __restrict__ sqs, int n) {
    __shared__ float red[256][4];
    int tid = threadIdx.x;
    int cp  = tid & 127;  // cols 2cp, 2cp+1
    int rg  = tid >> 7;   // 0..1
    float s0 = 0.f, q0 = 0.f, s1 = 0.f, q1 = 0.f;
    for (int r = blockIdx.x * 2 + rg; r < n; r += gridDim.x * 2) {
        float2 v = *reinterpret_cast<const float2*>(x + (size_t)r * 256 + cp * 2);
        s0 += v.x; q0 += v.x * v.x; s1 += v.y; q1 += v.y * v.y;
    }
    red[tid][0] = s0; red[tid][1] = q0; red[tid][2] = s1; red[tid][3] = q1;
    __syncthreads();
    if (tid < 128) {
        float a0 = red[tid][0] + red[tid + 128][0];
        float a1 = red[tid][1] + red[tid + 128][1];
        float a2 = red[tid][2] + red[tid + 128][2];
        float a3 = red[tid][3] + red[tid + 128][3];
        atomicAdd(&sums[tid * 2 + 0], a0);
        atomicAdd(&sqs [tid * 2 + 0], a1);
        atomicAdd(&sums[tid * 2 + 1], a2);
        atomicAdd(&sqs [tid * 2 + 1], a3);
    }
}

template <int F>
__global__ void bn_fin_k(const float* __restrict__ sums, const float* __restrict__ sqs,
                         const float* __restrict__ gamma, const float* __restrict__ beta,
                         float* __restrict__ scale, float* __restrict__ bias, float inv_n) {
    int c = threadIdx.x;
    if (c < F) {
        float m  = sums[c] * inv_n;
        float v  = sqs[c] * inv_n - m * m;
        float rs = rsqrtf(v + 1e-5f);
        float sc = gamma[c] * rs;
        scale[c] = sc;
        bias[c]  = beta[c] - m * sc;
    }
}

__global__ void norm_out_k(float* __restrict__ out, const float* __restrict__ scale,
                           const float* __restrict__ bias, int n4) {
    int i = blockIdx.x * blockDim.x + threadIdx.x;
    int stride = gridDim.x * blockDim.x;
    for (; i < n4; i += stride) {
        float4 v = reinterpret_cast<float4*>(out)[i];
        int c = (i * 4) & 255;
        float4 sc = *reinterpret_cast<const float4*>(scale + c);
        float4 bi = *reinterpret_cast<const float4*>(bias + c);
        v.x = fmaf(v.x, sc.x, bi.x);
        v.y = fmaf(v.y, sc.y, bi.y);
        v.z = fmaf(v.z, sc.z, bi.z);
        v.w = fmaf(v.w, sc.w, bi.w);
        reinterpret_cast<float4*>(out)[i] = v;
    }
}

// ---------------- launch ----------------

extern "C" void kernel_launch(void* const* d_in, const int* in_sizes, int n_in,
                              void* d_out, int out_size, void* d_ws, size_t ws_size,
                              hipStream_t stream) {
    const float* y      = (const float*)d_in[0];
    const int*   esrc   = (const int*)d_in[1];
    const int*   edst   = (const int*)d_in[2];
    const float* ew     = (const float*)d_in[3];
    const float* W1     = (const float*)d_in[4];
    const float* gamma1 = (const float*)d_in[5];
    const float* beta1  = (const float*)d_in[6];
    const float* W2     = (const float*)d_in[7];
    const float* gamma2 = (const float*)d_in[8];
    const float* beta2  = (const float*)d_in[9];
    float* out = (float*)d_out;

    char* ws = (char*)d_ws;
    size_t off = 0;
    auto alloc = [&](size_t bytes) -> void* {
        void* p = (void*)(ws + off);
        off += (bytes + 255) & ~(size_t)255;
        return p;
    };
    ushort_t* ybf  = (ushort_t*)alloc((size_t)NN * 64 * 2);
    ushort_t* t1   = (ushort_t*)alloc((size_t)NN * 64 * 2);
    ushort_t* h1   = (ushort_t*)alloc((size_t)NN * 128 * 2);
    ushort_t* a2   = (ushort_t*)alloc((size_t)NN * 128 * 2);
    ushort_t* w1t  = (ushort_t*)alloc(128 * 64 * 2);
    ushort_t* w2t  = (ushort_t*)alloc(256 * 128 * 2);
    int*   rp      = (int*)alloc((NN + 1) * 4);
    int*   cursor  = (int*)alloc(NN * 4);
    int*   deg     = (int*)alloc(NN * 4);
    int*   ssrc    = (int*)alloc((size_t)NE * 4);
    float* sw      = (float*)alloc((size_t)NE * 4);
    int*   partials= (int*)alloc(NBLK_SCAN * 4);
    float* stats   = (float*)alloc(768 * 4);
    float* colsum1 = stats;
    float* colsq1  = stats + 128;
    float* colsum2 = stats + 256;
    float* colsq2  = stats + 512;
    float* scale1  = (float*)alloc(128 * 4);
    float* bias1   = (float*)alloc(128 * 4);
    float* scale2  = (float*)alloc(256 * 4);
    float* bias2   = (float*)alloc(256 * 4);
    (void)alloc(64 * 1024);  // slack: gemm A-staging over-reads past row n (never stored)

    hipMemsetAsync(deg, 0, NN * 4, stream);
    hipMemsetAsync(stats, 0, 768 * 4, stream);

    // conversions (independent)
    cvt_y_k<<<(NN * 64 / 4 + 255) / 256, 256, 0, stream>>>(y, ybf, NN * 64 / 4);
    cvt_wt_k<<<(128 * 64 + 255) / 256, 256, 0, stream>>>(W1, w1t, 64, 128);
    cvt_wt_k<<<(256 * 128 + 255) / 256, 256, 0, stream>>>(W2, w2t, 128, 256);

    // CSR build (by dst)
    hist_k<<<(NE + 255) / 256, 256, 0, stream>>>(edst, deg, NE);
    scanA_k<<<NBLK_SCAN, 256, 0, stream>>>(deg, rp, partials, NN);
    scanB_k<<<1, 64, 0, stream>>>(partials, NBLK_SCAN);
    scanC_k<<<(NN + 255) / 256, 256, 0, stream>>>(rp, partials, cursor, NN, NE);
    scatter_k<<<(NE + 255) / 256, 256, 0, stream>>>(esrc, edst, ew, cursor, ssrc, sw, NE);

    // Layer 1: t1 = spmm(ybf); h1 = relu(t1 @ W1) in bf16; BN1 -> scale1/bias1
    spmm1_k<<<(NN + 3) / 4, 256, 0, stream>>>(ybf, rp, ssrc, sw, t1, NN);
    mgemm_k<64, true><<<dim3((NN + 63) / 64, 1), 256, 0, stream>>>(t1, w1t, h1, NN, 128);
    stats1_k<<<256, 256, 0, stream>>>(h1, colsum1, colsq1, NN);
    bn_fin_k<128><<<1, 128, 0, stream>>>(colsum1, colsq1, gamma1, beta1, scale1, bias1,
                                         1.0f / NN);

    // Layer 2: a2 = scale1*spmm(h1) + wsum*bias1 (bf16); out = relu(a2 @ W2); BN2 in place
    spmm2_k<<<(NN + 3) / 4, 256, 0, stream>>>(h1, rp, ssrc, sw, scale1, bias1, a2, NN);
    mgemm_k<128, false><<<dim3((NN + 63) / 64, 2), 256, 0, stream>>>(a2, w2t, out, NN, 256);
    stats2_k<<<256, 256, 0, stream>>>(out, colsum2, colsq2, NN);
    bn_fin_k<256><<<1, 256, 0, stream>>>(colsum2, colsq2, gamma2, beta2, scale2, bias2,
                                         1.0f / NN);
    norm_out_k<<<2048, 256, 0, stream>>>(out, scale2, bias2, NN * 256 / 4);
}

// Round 3
// 296.074 us; speedup vs baseline: 1.9052x; 1.2702x over previous
//
#include <hip/hip_runtime.h>

#define NN 50000
#define NE 800000

typedef unsigned short ushort_t;
typedef __attribute__((ext_vector_type(8))) short short8;
typedef __attribute__((ext_vector_type(4))) float f32x4;

constexpr int SCAN_CHUNK = 1024;
constexpr int NBLK_SCAN = (NN + SCAN_CHUNK - 1) / SCAN_CHUNK; // 49

// ---------------- bf16 helpers (bit-exact, RNE) ----------------
__device__ __forceinline__ float bf2f(ushort_t u) {
    union { unsigned int i; float f; } v;
    v.i = ((unsigned int)u) << 16;
    return v.f;
}
__device__ __forceinline__ float bf2f_u(unsigned int lo16) {  // low 16 bits
    union { unsigned int i; float f; } v;
    v.i = lo16 << 16;
    return v.f;
}
__device__ __forceinline__ ushort_t f2bf(float f) {
    union { float f; unsigned int u; } v;
    v.f = f;
    unsigned int r = (v.u + 0x7fffu + ((v.u >> 16) & 1u)) >> 16;
    return (ushort_t)r;
}

// ---------------- CSR build ----------------

__global__ void hist_k(const int* __restrict__ dst, int* __restrict__ deg, int E) {
    int e = blockIdx.x * blockDim.x + threadIdx.x;
    if (e < E) atomicAdd(&deg[dst[e]], 1);
}

__global__ void scanA_k(const int* __restrict__ deg, int* __restrict__ rp,
                        int* __restrict__ partials, int n) {
    __shared__ int sm[256];
    int tid = threadIdx.x;
    int base = blockIdx.x * SCAN_CHUNK + tid * 4;
    int v0 = (base + 0 < n) ? deg[base + 0] : 0;
    int v1 = (base + 1 < n) ? deg[base + 1] : 0;
    int v2 = (base + 2 < n) ? deg[base + 2] : 0;
    int v3 = (base + 3 < n) ? deg[base + 3] : 0;
    int s = v0 + v1 + v2 + v3;
    sm[tid] = s;
    __syncthreads();
    for (int off = 1; off < 256; off <<= 1) {
        int t = (tid >= off) ? sm[tid - off] : 0;
        __syncthreads();
        sm[tid] += t;
        __syncthreads();
    }
    int excl = sm[tid] - s;
    if (base + 0 < n) rp[base + 0] = excl;
    if (base + 1 < n) rp[base + 1] = excl + v0;
    if (base + 2 < n) rp[base + 2] = excl + v0 + v1;
    if (base + 3 < n) rp[base + 3] = excl + v0 + v1 + v2;
    if (tid == 255) partials[blockIdx.x] = sm[255];
}

__global__ void scanB_k(int* __restrict__ partials, int nblk) {
    if (threadIdx.x == 0 && blockIdx.x == 0) {
        int run = 0;
        for (int b = 0; b < nblk; ++b) {
            int v = partials[b];
            partials[b] = run;
            run += v;
        }
    }
}

__global__ void scanC_k(int* __restrict__ rp, const int* __restrict__ partials,
                        int* __restrict__ cursor, int n, int E) {
    int i = blockIdx.x * blockDim.x + threadIdx.x;
    if (i < n) {
        int v = rp[i] + partials[i >> 10];
        rp[i] = v;
        cursor[i] = v;
    }
    if (i == 0) rp[n] = E;
}

__global__ void scatter_k(const int* __restrict__ src, const int* __restrict__ dst,
                          const float* __restrict__ w, int* __restrict__ cursor,
                          int* __restrict__ ssrc, float* __restrict__ sw, int E) {
    int e = blockIdx.x * blockDim.x + threadIdx.x;
    if (e < E) {
        int d = dst[e];
        int p = atomicAdd(&cursor[d], 1);
        ssrc[p] = src[e];
        sw[p]  = w[e];
    }
}

// ---------------- conversions ----------------

__global__ void cvt_y_k(const float* __restrict__ in, ushort_t* __restrict__ out, int n4) {
    int i = blockIdx.x * blockDim.x + threadIdx.x;
    if (i < n4) {
        float4 v = reinterpret_cast<const float4*>(in)[i];
        ushort4 o;
        o.x = f2bf(v.x); o.y = f2bf(v.y); o.z = f2bf(v.z); o.w = f2bf(v.w);
        reinterpret_cast<ushort4*>(out)[i] = o;
    }
}

// WT[c][k] = bf( W[k][c] ),  W is [Kd x Nd] row-major
__global__ void cvt_wt_k(const float* __restrict__ W, ushort_t* __restrict__ WT,
                         int Kd, int Nd) {
    int i = blockIdx.x * blockDim.x + threadIdx.x;
    if (i < Kd * Nd) {
        int c = i / Kd;
        int k = i - c * Kd;
        WT[i] = f2bf(W[k * Nd + c]);
    }
}

// ---------------- SpMM (bf16 gather, one wave per node, 4 edges in flight) --------

__global__ void spmm1_k(const ushort_t* __restrict__ yb, const int* __restrict__ rp,
                        const int* __restrict__ ssrc, const float* __restrict__ sw,
                        ushort_t* __restrict__ t1, int n) {
    int wid  = (blockIdx.x * blockDim.x + threadIdx.x) >> 6;
    int lane = threadIdx.x & 63;
    if (wid >= n) return;
    int beg = rp[wid], end = rp[wid + 1];
    float acc = 0.f;
    int p = beg;
    for (; p + 4 <= end; p += 4) {
        int s0 = ssrc[p + 0], s1 = ssrc[p + 1], s2 = ssrc[p + 2], s3 = ssrc[p + 3];
        float w0 = sw[p + 0], w1 = sw[p + 1], w2 = sw[p + 2], w3 = sw[p + 3];
        ushort_t u0 = yb[(size_t)s0 * 64 + lane];
        ushort_t u1 = yb[(size_t)s1 * 64 + lane];
        ushort_t u2 = yb[(size_t)s2 * 64 + lane];
        ushort_t u3 = yb[(size_t)s3 * 64 + lane];
        acc = fmaf(w0, bf2f(u0), acc);
        acc = fmaf(w1, bf2f(u1), acc);
        acc = fmaf(w2, bf2f(u2), acc);
        acc = fmaf(w3, bf2f(u3), acc);
    }
    for (; p < end; ++p)
        acc = fmaf(sw[p], bf2f(yb[(size_t)ssrc[p] * 64 + lane]), acc);
    t1[(size_t)wid * 64 + lane] = f2bf(acc);
}

// gather h1 (bf16, 128 cols, 2/lane), fold BN1: a2 = acc*scale1 + wsum*bias1
__global__ void spmm2_k(const ushort_t* __restrict__ h1, const int* __restrict__ rp,
                        const int* __restrict__ ssrc, const float* __restrict__ sw,
                        const float* __restrict__ scale1, const float* __restrict__ bias1,
                        ushort_t* __restrict__ a2, int n) {
    int wid  = (blockIdx.x * blockDim.x + threadIdx.x) >> 6;
    int lane = threadIdx.x & 63;
    if (wid >= n) return;
    int beg = rp[wid], end = rp[wid + 1];
    float a0 = 0.f, a1 = 0.f, wacc = 0.f;
    int p = beg;
    for (; p + 4 <= end; p += 4) {
        int s0 = ssrc[p + 0], s1 = ssrc[p + 1], s2 = ssrc[p + 2], s3 = ssrc[p + 3];
        float w0 = sw[p + 0], w1 = sw[p + 1], w2 = sw[p + 2], w3 = sw[p + 3];
        unsigned int u0 = *reinterpret_cast<const unsigned int*>(h1 + (size_t)s0 * 128 + lane * 2);
        unsigned int u1 = *reinterpret_cast<const unsigned int*>(h1 + (size_t)s1 * 128 + lane * 2);
        unsigned int u2 = *reinterpret_cast<const unsigned int*>(h1 + (size_t)s2 * 128 + lane * 2);
        unsigned int u3 = *reinterpret_cast<const unsigned int*>(h1 + (size_t)s3 * 128 + lane * 2);
        wacc += w0 + w1 + w2 + w3;
        a0 = fmaf(w0, bf2f_u(u0 & 0xffffu), a0); a1 = fmaf(w0, bf2f_u(u0 >> 16), a1);
        a0 = fmaf(w1, bf2f_u(u1 & 0xffffu), a0); a1 = fmaf(w1, bf2f_u(u1 >> 16), a1);
        a0 = fmaf(w2, bf2f_u(u2 & 0xffffu), a0); a1 = fmaf(w2, bf2f_u(u2 >> 16), a1);
        a0 = fmaf(w3, bf2f_u(u3 & 0xffffu), a0); a1 = fmaf(w3, bf2f_u(u3 >> 16), a1);
    }
    for (; p < end; ++p) {
        int s    = ssrc[p];
        float wt = sw[p];
        wacc += wt;
        unsigned int u = *reinterpret_cast<const unsigned int*>(h1 + (size_t)s * 128 + lane * 2);
        a0 = fmaf(wt, bf2f_u(u & 0xffffu), a0);
        a1 = fmaf(wt, bf2f_u(u >> 16), a1);
    }
    float2 sc = *reinterpret_cast<const float2*>(scale1 + lane * 2);
    float2 bi = *reinterpret_cast<const float2*>(bias1 + lane * 2);
    unsigned int o = (unsigned int)f2bf(fmaf(a0, sc.x, wacc * bi.x))
                   | ((unsigned int)f2bf(fmaf(a1, sc.y, wacc * bi.y)) << 16);
    *reinterpret_cast<unsigned int*>(a2 + (size_t)wid * 128 + lane * 2) = o;
}

// ---------------- MFMA GEMM + fused BN stats ----------------
// C[n x N] = relu( A[n x K](bf16) @ BT[N x K](bf16)^T ); also accumulates per-column
// sum / sum-sq of the relu'd fp32 output into colsum/colsq (global atomics, one per
// column per block after an LDS reduce). Block: 4 waves (2x2), tile 64 x 128.
// A staged in LDS with XOR swizzle byte^=(row&7)<<4 (guide §6 G4).

template <int K, bool OUT_BF16>
__launch_bounds__(256)
__global__ void mgemm_k(const ushort_t* __restrict__ A, const ushort_t* __restrict__ BT,
                        void* __restrict__ Cout, float* __restrict__ colsum,
                        float* __restrict__ colsq, int n, int N) {
    constexpr int K2 = K * 2;            // row bytes
    __shared__ char As[64 * K2];
    __shared__ float lsum[128], lsq[128];
    int tid = threadIdx.x;
    int r0  = blockIdx.x * 64;
    int c0  = blockIdx.y * 128;

    if (tid < 128) { lsum[tid] = 0.f; lsq[tid] = 0.f; }

    // Stage A-tile (rows past n read workspace slack; never stored)
    {
        const char* Ab = (const char*)(A + (size_t)r0 * K);
#pragma unroll
        for (int it = 0; it < (64 * K2) / 4096; ++it) {
            int p   = (it * 256 + tid) * 16;
            int row = p / K2;
            int cb  = p - row * K2;
            short8 v = *reinterpret_cast<const short8*>(Ab + p);
            *reinterpret_cast<short8*>(As + row * K2 + (cb ^ ((row & 7) << 4))) = v;
        }
    }

    int lane = tid & 63;
    int w    = tid >> 6;
    int wm0  = (w >> 1) * 32;
    int wn0  = (w & 1) * 64;
    int kg   = lane >> 4;
    int lr   = lane & 15;

    // Preload all B fragments
    short8 bfrag[K / 32][4];
#pragma unroll
    for (int fn = 0; fn < 4; ++fn) {
        const ushort_t* bp = BT + (size_t)(c0 + wn0 + fn * 16 + lr) * K + kg * 8;
#pragma unroll
        for (int ks = 0; ks < K / 32; ++ks)
            bfrag[ks][fn] = *reinterpret_cast<const short8*>(bp + ks * 32);
    }

    __syncthreads();

    f32x4 acc[2][4];
#pragma unroll
    for (int i = 0; i < 2; ++i)
#pragma unroll
        for (int j = 0; j < 4; ++j) acc[i][j] = f32x4{0.f, 0.f, 0.f, 0.f};

#pragma unroll
    for (int ks = 0; ks < K / 32; ++ks) {
        int boff = ks * 64 + kg * 16;
        int row0 = wm0 + lr;
        int row1 = wm0 + 16 + lr;
        short8 a0 = *reinterpret_cast<const short8*>(As + row0 * K2 + (boff ^ ((row0 & 7) << 4)));
        short8 a1 = *reinterpret_cast<const short8*>(As + row1 * K2 + (boff ^ ((row1 & 7) << 4)));
#pragma unroll
        for (int fn = 0; fn < 4; ++fn) {
            acc[0][fn] = __builtin_amdgcn_mfma_f32_16x16x32_bf16(a0, bfrag[ks][fn], acc[0][fn], 0, 0, 0);
            acc[1][fn] = __builtin_amdgcn_mfma_f32_16x16x32_bf16(a1, bfrag[ks][fn], acc[1][fn], 0, 0, 0);
        }
    }

    // Epilogue: relu + store + per-thread column stat partials
    float s_c[4] = {0.f, 0.f, 0.f, 0.f};
    float q_c[4] = {0.f, 0.f, 0.f, 0.f};
#pragma unroll
    for (int fm = 0; fm < 2; ++fm) {
        int rowb = r0 + wm0 + fm * 16 + kg * 4;
#pragma unroll
        for (int i = 0; i < 4; ++i) {
            int r = rowb + i;
            if (r < n) {
#pragma unroll
                for (int fn = 0; fn < 4; ++fn) {
                    float v = fmaxf(acc[fm][fn][i], 0.f);
                    s_c[fn] += v;
                    q_c[fn] += v * v;
                    int c = c0 + wn0 + fn * 16 + lr;
                    if constexpr (OUT_BF16)
                        ((ushort_t*)Cout)[(size_t)r * N + c] = f2bf(v);
                    else
                        ((float*)Cout)[(size_t)r * N + c] = v;
                }
            }
        }
    }
#pragma unroll
    for (int fn = 0; fn < 4; ++fn) {
        int c = wn0 + fn * 16 + lr;
        atomicAdd(&lsum[c], s_c[fn]);
        atomicAdd(&lsq[c], q_c[fn]);
    }
    __syncthreads();
    if (tid < 128) {
        atomicAdd(&colsum[c0 + tid], lsum[tid]);
        atomicAdd(&colsq[c0 + tid], lsq[tid]);
    }
}

// ---------------- BatchNorm finalize + apply ----------------

template <int F>
__global__ void bn_fin_k(const float* __restrict__ sums, const float* __restrict__ sqs,
                         const float* __restrict__ gamma, const float* __restrict__ beta,
                         float* __restrict__ scale, float* __restrict__ bias, float inv_n) {
    int c = threadIdx.x;
    if (c < F) {
        float m  = sums[c] * inv_n;
        float v  = sqs[c] * inv_n - m * m;
        float rs = rsqrtf(v + 1e-5f);
        float sc = gamma[c] * rs;
        scale[c] = sc;
        bias[c]  = beta[c] - m * sc;
    }
}

__global__ void norm_out_k(float* __restrict__ out, const float* __restrict__ scale,
                           const float* __restrict__ bias, int n4) {
    int i = blockIdx.x * blockDim.x + threadIdx.x;
    int stride = gridDim.x * blockDim.x;
    for (; i < n4; i += stride) {
        float4 v = reinterpret_cast<float4*>(out)[i];
        int c = (i * 4) & 255;
        float4 sc = *reinterpret_cast<const float4*>(scale + c);
        float4 bi = *reinterpret_cast<const float4*>(bias + c);
        v.x = fmaf(v.x, sc.x, bi.x);
        v.y = fmaf(v.y, sc.y, bi.y);
        v.z = fmaf(v.z, sc.z, bi.z);
        v.w = fmaf(v.w, sc.w, bi.w);
        reinterpret_cast<float4*>(out)[i] = v;
    }
}

// ---------------- launch ----------------

extern "C" void kernel_launch(void* const* d_in, const int* in_sizes, int n_in,
                              void* d_out, int out_size, void* d_ws, size_t ws_size,
                              hipStream_t stream) {
    const float* y      = (const float*)d_in[0];
    const int*   esrc   = (const int*)d_in[1];
    const int*   edst   = (const int*)d_in[2];
    const float* ew     = (const float*)d_in[3];
    const float* W1     = (const float*)d_in[4];
    const float* gamma1 = (const float*)d_in[5];
    const float* beta1  = (const float*)d_in[6];
    const float* W2     = (const float*)d_in[7];
    const float* gamma2 = (const float*)d_in[8];
    const float* beta2  = (const float*)d_in[9];
    float* out = (float*)d_out;

    char* ws = (char*)d_ws;
    size_t off = 0;
    auto alloc = [&](size_t bytes) -> void* {
        void* p = (void*)(ws + off);
        off += (bytes + 255) & ~(size_t)255;
        return p;
    };
    ushort_t* ybf  = (ushort_t*)alloc((size_t)NN * 64 * 2);
    ushort_t* t1   = (ushort_t*)alloc((size_t)NN * 64 * 2);
    ushort_t* h1   = (ushort_t*)alloc((size_t)NN * 128 * 2);
    ushort_t* a2   = (ushort_t*)alloc((size_t)NN * 128 * 2);
    ushort_t* w1t  = (ushort_t*)alloc(128 * 64 * 2);
    ushort_t* w2t  = (ushort_t*)alloc(256 * 128 * 2);
    int*   rp      = (int*)alloc((NN + 1) * 4);
    int*   cursor  = (int*)alloc(NN * 4);
    int*   deg     = (int*)alloc(NN * 4);
    int*   ssrc    = (int*)alloc((size_t)NE * 4);
    float* sw      = (float*)alloc((size_t)NE * 4);
    int*   partials= (int*)alloc(NBLK_SCAN * 4);
    float* stats   = (float*)alloc(768 * 4);
    float* colsum1 = stats;
    float* colsq1  = stats + 128;
    float* colsum2 = stats + 256;
    float* colsq2  = stats + 512;
    float* scale1  = (float*)alloc(128 * 4);
    float* bias1   = (float*)alloc(128 * 4);
    float* scale2  = (float*)alloc(256 * 4);
    float* bias2   = (float*)alloc(256 * 4);
    (void)alloc(64 * 1024);  // slack: gemm A-staging over-reads past row n (never stored)

    hipMemsetAsync(deg, 0, NN * 4, stream);
    hipMemsetAsync(stats, 0, 768 * 4, stream);

    // conversions (independent)
    cvt_y_k<<<(NN * 64 / 4 + 255) / 256, 256, 0, stream>>>(y, ybf, NN * 64 / 4);
    cvt_wt_k<<<(128 * 64 + 255) / 256, 256, 0, stream>>>(W1, w1t, 64, 128);
    cvt_wt_k<<<(256 * 128 + 255) / 256, 256, 0, stream>>>(W2, w2t, 128, 256);

    // CSR build (by dst)
    hist_k<<<(NE + 255) / 256, 256, 0, stream>>>(edst, deg, NE);
    scanA_k<<<NBLK_SCAN, 256, 0, stream>>>(deg, rp, partials, NN);
    scanB_k<<<1, 64, 0, stream>>>(partials, NBLK_SCAN);
    scanC_k<<<(NN + 255) / 256, 256, 0, stream>>>(rp, partials, cursor, NN, NE);
    scatter_k<<<(NE + 255) / 256, 256, 0, stream>>>(esrc, edst, ew, cursor, ssrc, sw, NE);

    // Layer 1: t1 = spmm(ybf); h1 = relu(t1 @ W1) bf16 + fused BN1 stats
    spmm1_k<<<(NN + 3) / 4, 256, 0, stream>>>(ybf, rp, ssrc, sw, t1, NN);
    mgemm_k<64, true><<<dim3((NN + 63) / 64, 1), 256, 0, stream>>>(
        t1, w1t, h1, colsum1, colsq1, NN, 128);
    bn_fin_k<128><<<1, 128, 0, stream>>>(colsum1, colsq1, gamma1, beta1, scale1, bias1,
                                         1.0f / NN);

    // Layer 2: a2 = scale1*spmm(h1) + wsum*bias1 (bf16); out = relu(a2 @ W2) + BN2 stats
    spmm2_k<<<(NN + 3) / 4, 256, 0, stream>>>(h1, rp, ssrc, sw, scale1, bias1, a2, NN);
    mgemm_k<128, false><<<dim3((NN + 63) / 64, 2), 256, 0, stream>>>(
        a2, w2t, out, colsum2, colsq2, NN, 256);
    bn_fin_k<256><<<1, 256, 0, stream>>>(colsum2, colsq2, gamma2, beta2, scale2, bias2,
                                         1.0f / NN);
    norm_out_k<<<2048, 256, 0, stream>>>(out, scale2, bias2, NN * 256 / 4);
}

// Round 4
// 286.525 us; speedup vs baseline: 1.9687x; 1.0333x over previous
//
#include <hip/hip_runtime.h>

#define NN 50000
#define NE 800000

typedef unsigned short ushort_t;
typedef __attribute__((ext_vector_type(8))) short short8;
typedef __attribute__((ext_vector_type(4))) float f32x4;

constexpr int SCAN_CHUNK = 1024;
constexpr int NBLK_SCAN = (NN + SCAN_CHUNK - 1) / SCAN_CHUNK; // 49

// ---------------- bf16 helpers (bit-exact, RNE) ----------------
__device__ __forceinline__ float bf2f(ushort_t u) {
    union { unsigned int i; float f; } v;
    v.i = ((unsigned int)u) << 16;
    return v.f;
}
__device__ __forceinline__ float bf2f_u(unsigned int lo16) {  // low 16 bits hold bf16
    union { unsigned int i; float f; } v;
    v.i = lo16 << 16;
    return v.f;
}
__device__ __forceinline__ float hi16_as_f(unsigned int u) {  // high 16 bits hold bf16
    union { unsigned int i; float f; } v;
    v.i = u & 0xffff0000u;
    return v.f;
}
__device__ __forceinline__ ushort_t f2bf(float f) {
    union { float f; unsigned int u; } v;
    v.f = f;
    unsigned int r = (v.u + 0x7fffu + ((v.u >> 16) & 1u)) >> 16;
    return (ushort_t)r;
}

// ---------------- CSR build ----------------

__global__ void hist_k(const int* __restrict__ dst, int* __restrict__ deg, int E) {
    int e = blockIdx.x * blockDim.x + threadIdx.x;
    if (e < E) atomicAdd(&deg[dst[e]], 1);
}

__global__ void scanA_k(const int* __restrict__ deg, int* __restrict__ rp,
                        int* __restrict__ partials, int n) {
    __shared__ int sm[256];
    int tid = threadIdx.x;
    int base = blockIdx.x * SCAN_CHUNK + tid * 4;
    int v0 = (base + 0 < n) ? deg[base + 0] : 0;
    int v1 = (base + 1 < n) ? deg[base + 1] : 0;
    int v2 = (base + 2 < n) ? deg[base + 2] : 0;
    int v3 = (base + 3 < n) ? deg[base + 3] : 0;
    int s = v0 + v1 + v2 + v3;
    sm[tid] = s;
    __syncthreads();
    for (int off = 1; off < 256; off <<= 1) {
        int t = (tid >= off) ? sm[tid - off] : 0;
        __syncthreads();
        sm[tid] += t;
        __syncthreads();
    }
    int excl = sm[tid] - s;
    if (base + 0 < n) rp[base + 0] = excl;
    if (base + 1 < n) rp[base + 1] = excl + v0;
    if (base + 2 < n) rp[base + 2] = excl + v0 + v1;
    if (base + 3 < n) rp[base + 3] = excl + v0 + v1 + v2;
    if (tid == 255) partials[blockIdx.x] = sm[255];
}

__global__ void scanB_k(int* __restrict__ partials, int nblk) {
    if (threadIdx.x == 0 && blockIdx.x == 0) {
        int run = 0;
        for (int b = 0; b < nblk; ++b) {
            int v = partials[b];
            partials[b] = run;
            run += v;
        }
    }
}

__global__ void scanC_k(int* __restrict__ rp, const int* __restrict__ partials,
                        int* __restrict__ cursor, int n, int E) {
    int i = blockIdx.x * blockDim.x + threadIdx.x;
    if (i < n) {
        int v = rp[i] + partials[i >> 10];
        rp[i] = v;
        cursor[i] = v;
    }
    if (i == 0) rp[n] = E;
}

// Pack edge -> single 4B word: [ w_bf16 (hi16) | src (lo16) ]   (NN < 65536)
__global__ void scatter_k(const int* __restrict__ src, const int* __restrict__ dst,
                          const float* __restrict__ w, int* __restrict__ cursor,
                          unsigned int* __restrict__ epack, int E) {
    int e = blockIdx.x * blockDim.x + threadIdx.x;
    if (e < E) {
        int d = dst[e];
        int p = atomicAdd(&cursor[d], 1);
        epack[p] = ((unsigned int)f2bf(w[e]) << 16) | (unsigned int)src[e];
    }
}

// ---------------- conversions ----------------

__global__ void cvt_y_k(const float* __restrict__ in, ushort_t* __restrict__ out, int n4) {
    int i = blockIdx.x * blockDim.x + threadIdx.x;
    if (i < n4) {
        float4 v = reinterpret_cast<const float4*>(in)[i];
        ushort4 o;
        o.x = f2bf(v.x); o.y = f2bf(v.y); o.z = f2bf(v.z); o.w = f2bf(v.w);
        reinterpret_cast<ushort4*>(out)[i] = o;
    }
}

// WT[c][k] = bf( W[k][c] ),  W is [Kd x Nd] row-major
__global__ void cvt_wt_k(const float* __restrict__ W, ushort_t* __restrict__ WT,
                         int Kd, int Nd) {
    int i = blockIdx.x * blockDim.x + threadIdx.x;
    if (i < Kd * Nd) {
        int c = i / Kd;
        int k = i - c * Kd;
        WT[i] = f2bf(W[k * Nd + c]);
    }
}

// ---------------- SpMM (bf16 gather, one wave per node, 8 edges in flight) --------

__global__ void spmm1_k(const ushort_t* __restrict__ yb, const int* __restrict__ rp,
                        const unsigned int* __restrict__ ep,
                        ushort_t* __restrict__ t1, int n) {
    int wid  = (blockIdx.x * blockDim.x + threadIdx.x) >> 6;
    int lane = threadIdx.x & 63;
    if (wid >= n) return;
    int beg = rp[wid], end = rp[wid + 1];
    float acc = 0.f;
    int p = beg;
    for (; p + 8 <= end; p += 8) {
        unsigned int m[8];
#pragma unroll
        for (int j = 0; j < 8; ++j) m[j] = ep[p + j];
        ushort_t u[8];
#pragma unroll
        for (int j = 0; j < 8; ++j)
            u[j] = yb[(size_t)(m[j] & 0xffffu) * 64 + lane];
#pragma unroll
        for (int j = 0; j < 8; ++j)
            acc = fmaf(hi16_as_f(m[j]), bf2f(u[j]), acc);
    }
    for (; p < end; ++p) {
        unsigned int m = ep[p];
        acc = fmaf(hi16_as_f(m), bf2f(yb[(size_t)(m & 0xffffu) * 64 + lane]), acc);
    }
    t1[(size_t)wid * 64 + lane] = f2bf(acc);
}

// gather h1 (bf16, 128 cols, 2/lane), fold BN1: a2 = acc*scale1 + wsum*bias1
__global__ void spmm2_k(const ushort_t* __restrict__ h1, const int* __restrict__ rp,
                        const unsigned int* __restrict__ ep,
                        const float* __restrict__ scale1, const float* __restrict__ bias1,
                        ushort_t* __restrict__ a2, int n) {
    int wid  = (blockIdx.x * blockDim.x + threadIdx.x) >> 6;
    int lane = threadIdx.x & 63;
    if (wid >= n) return;
    int beg = rp[wid], end = rp[wid + 1];
    float a0 = 0.f, a1 = 0.f, wacc = 0.f;
    int p = beg;
    for (; p + 8 <= end; p += 8) {
        unsigned int m[8];
#pragma unroll
        for (int j = 0; j < 8; ++j) m[j] = ep[p + j];
        unsigned int u[8];
#pragma unroll
        for (int j = 0; j < 8; ++j)
            u[j] = *reinterpret_cast<const unsigned int*>(
                h1 + (size_t)(m[j] & 0xffffu) * 128 + lane * 2);
#pragma unroll
        for (int j = 0; j < 8; ++j) {
            float wt = hi16_as_f(m[j]);
            wacc += wt;
            a0 = fmaf(wt, bf2f_u(u[j] & 0xffffu), a0);
            a1 = fmaf(wt, bf2f_u(u[j] >> 16), a1);
        }
    }
    for (; p < end; ++p) {
        unsigned int m = ep[p];
        float wt = hi16_as_f(m);
        wacc += wt;
        unsigned int u = *reinterpret_cast<const unsigned int*>(
            h1 + (size_t)(m & 0xffffu) * 128 + lane * 2);
        a0 = fmaf(wt, bf2f_u(u & 0xffffu), a0);
        a1 = fmaf(wt, bf2f_u(u >> 16), a1);
    }
    float2 sc = *reinterpret_cast<const float2*>(scale1 + lane * 2);
    float2 bi = *reinterpret_cast<const float2*>(bias1 + lane * 2);
    unsigned int o = (unsigned int)f2bf(fmaf(a0, sc.x, wacc * bi.x))
                   | ((unsigned int)f2bf(fmaf(a1, sc.y, wacc * bi.y)) << 16);
    *reinterpret_cast<unsigned int*>(a2 + (size_t)wid * 128 + lane * 2) = o;
}

// ---------------- MFMA GEMM + fused BN stats ----------------
// C[n x N] = relu( A[n x K](bf16) @ BT[N x K](bf16)^T ); accumulates per-column
// sum / sum-sq of the relu'd fp32 output (LDS reduce -> 1 global atomic/col/block).
// Block: 4 waves (2x2), tile 64 x 128. A staged in LDS with XOR swizzle
// byte^=(row&7)<<4 (guide §6 G4).

template <int K, bool OUT_BF16>
__launch_bounds__(256)
__global__ void mgemm_k(const ushort_t* __restrict__ A, const ushort_t* __restrict__ BT,
                        void* __restrict__ Cout, float* __restrict__ colsum,
                        float* __restrict__ colsq, int n, int N) {
    constexpr int K2 = K * 2;            // row bytes
    __shared__ char As[64 * K2];
    __shared__ float lsum[128], lsq[128];
    int tid = threadIdx.x;
    int r0  = blockIdx.x * 64;
    int c0  = blockIdx.y * 128;

    if (tid < 128) { lsum[tid] = 0.f; lsq[tid] = 0.f; }

    // Stage A-tile (rows past n read workspace slack; never stored)
    {
        const char* Ab = (const char*)(A + (size_t)r0 * K);
#pragma unroll
        for (int it = 0; it < (64 * K2) / 4096; ++it) {
            int p   = (it * 256 + tid) * 16;
            int row = p / K2;
            int cb  = p - row * K2;
            short8 v = *reinterpret_cast<const short8*>(Ab + p);
            *reinterpret_cast<short8*>(As + row * K2 + (cb ^ ((row & 7) << 4))) = v;
        }
    }

    int lane = tid & 63;
    int w    = tid >> 6;
    int wm0  = (w >> 1) * 32;
    int wn0  = (w & 1) * 64;
    int kg   = lane >> 4;
    int lr   = lane & 15;

    // Preload all B fragments
    short8 bfrag[K / 32][4];
#pragma unroll
    for (int fn = 0; fn < 4; ++fn) {
        const ushort_t* bp = BT + (size_t)(c0 + wn0 + fn * 16 + lr) * K + kg * 8;
#pragma unroll
        for (int ks = 0; ks < K / 32; ++ks)
            bfrag[ks][fn] = *reinterpret_cast<const short8*>(bp + ks * 32);
    }

    __syncthreads();

    f32x4 acc[2][4];
#pragma unroll
    for (int i = 0; i < 2; ++i)
#pragma unroll
        for (int j = 0; j < 4; ++j) acc[i][j] = f32x4{0.f, 0.f, 0.f, 0.f};

#pragma unroll
    for (int ks = 0; ks < K / 32; ++ks) {
        int boff = ks * 64 + kg * 16;
        int row0 = wm0 + lr;
        int row1 = wm0 + 16 + lr;
        short8 a0 = *reinterpret_cast<const short8*>(As + row0 * K2 + (boff ^ ((row0 & 7) << 4)));
        short8 a1 = *reinterpret_cast<const short8*>(As + row1 * K2 + (boff ^ ((row1 & 7) << 4)));
#pragma unroll
        for (int fn = 0; fn < 4; ++fn) {
            acc[0][fn] = __builtin_amdgcn_mfma_f32_16x16x32_bf16(a0, bfrag[ks][fn], acc[0][fn], 0, 0, 0);
            acc[1][fn] = __builtin_amdgcn_mfma_f32_16x16x32_bf16(a1, bfrag[ks][fn], acc[1][fn], 0, 0, 0);
        }
    }

    // Epilogue: relu + store + per-thread column stat partials
    float s_c[4] = {0.f, 0.f, 0.f, 0.f};
    float q_c[4] = {0.f, 0.f, 0.f, 0.f};
#pragma unroll
    for (int fm = 0; fm < 2; ++fm) {
        int rowb = r0 + wm0 + fm * 16 + kg * 4;
#pragma unroll
        for (int i = 0; i < 4; ++i) {
            int r = rowb + i;
            if (r < n) {
#pragma unroll
                for (int fn = 0; fn < 4; ++fn) {
                    float v = fmaxf(acc[fm][fn][i], 0.f);
                    s_c[fn] += v;
                    q_c[fn] += v * v;
                    int c = c0 + wn0 + fn * 16 + lr;
                    if constexpr (OUT_BF16)
                        ((ushort_t*)Cout)[(size_t)r * N + c] = f2bf(v);
                    else
                        ((float*)Cout)[(size_t)r * N + c] = v;
                }
            }
        }
    }
#pragma unroll
    for (int fn = 0; fn < 4; ++fn) {
        int c = wn0 + fn * 16 + lr;
        atomicAdd(&lsum[c], s_c[fn]);
        atomicAdd(&lsq[c], q_c[fn]);
    }
    __syncthreads();
    if (tid < 128) {
        atomicAdd(&colsum[c0 + tid], lsum[tid]);
        atomicAdd(&colsq[c0 + tid], lsq[tid]);
    }
}

// ---------------- BatchNorm finalize + apply ----------------

template <int F>
__global__ void bn_fin_k(const float* __restrict__ sums, const float* __restrict__ sqs,
                         const float* __restrict__ gamma, const float* __restrict__ beta,
                         float* __restrict__ scale, float* __restrict__ bias, float inv_n) {
    int c = threadIdx.x;
    if (c < F) {
        float m  = sums[c] * inv_n;
        float v  = sqs[c] * inv_n - m * m;
        float rs = rsqrtf(v + 1e-5f);
        float sc = gamma[c] * rs;
        scale[c] = sc;
        bias[c]  = beta[c] - m * sc;
    }
}

__global__ void norm_out_k(float* __restrict__ out, const float* __restrict__ scale,
                           const float* __restrict__ bias, int n4) {
    int i = blockIdx.x * blockDim.x + threadIdx.x;
    int stride = gridDim.x * blockDim.x;
    for (; i < n4; i += stride) {
        float4 v = reinterpret_cast<float4*>(out)[i];
        int c = (i * 4) & 255;
        float4 sc = *reinterpret_cast<const float4*>(scale + c);
        float4 bi = *reinterpret_cast<const float4*>(bias + c);
        v.x = fmaf(v.x, sc.x, bi.x);
        v.y = fmaf(v.y, sc.y, bi.y);
        v.z = fmaf(v.z, sc.z, bi.z);
        v.w = fmaf(v.w, sc.w, bi.w);
        reinterpret_cast<float4*>(out)[i] = v;
    }
}

// ---------------- launch ----------------

extern "C" void kernel_launch(void* const* d_in, const int* in_sizes, int n_in,
                              void* d_out, int out_size, void* d_ws, size_t ws_size,
                              hipStream_t stream) {
    const float* y      = (const float*)d_in[0];
    const int*   esrc   = (const int*)d_in[1];
    const int*   edst   = (const int*)d_in[2];
    const float* ew     = (const float*)d_in[3];
    const float* W1     = (const float*)d_in[4];
    const float* gamma1 = (const float*)d_in[5];
    const float* beta1  = (const float*)d_in[6];
    const float* W2     = (const float*)d_in[7];
    const float* gamma2 = (const float*)d_in[8];
    const float* beta2  = (const float*)d_in[9];
    float* out = (float*)d_out;

    char* ws = (char*)d_ws;
    size_t off = 0;
    auto alloc = [&](size_t bytes) -> void* {
        void* p = (void*)(ws + off);
        off += (bytes + 255) & ~(size_t)255;
        return p;
    };
    ushort_t* ybf  = (ushort_t*)alloc((size_t)NN * 64 * 2);
    ushort_t* t1   = (ushort_t*)alloc((size_t)NN * 64 * 2);
    ushort_t* h1   = (ushort_t*)alloc((size_t)NN * 128 * 2);
    ushort_t* a2   = (ushort_t*)alloc((size_t)NN * 128 * 2);
    ushort_t* w1t  = (ushort_t*)alloc(128 * 64 * 2);
    ushort_t* w2t  = (ushort_t*)alloc(256 * 128 * 2);
    int*   rp      = (int*)alloc((NN + 1) * 4);
    int*   cursor  = (int*)alloc(NN * 4);
    int*   deg     = (int*)alloc(NN * 4);
    unsigned int* epack = (unsigned int*)alloc((size_t)NE * 4);
    int*   partials= (int*)alloc(NBLK_SCAN * 4);
    float* stats   = (float*)alloc(768 * 4);
    float* colsum1 = stats;
    float* colsq1  = stats + 128;
    float* colsum2 = stats + 256;
    float* colsq2  = stats + 512;
    float* scale1  = (float*)alloc(128 * 4);
    float* bias1   = (float*)alloc(128 * 4);
    float* scale2  = (float*)alloc(256 * 4);
    float* bias2   = (float*)alloc(256 * 4);
    (void)alloc(64 * 1024);  // slack: gemm A-staging over-reads past row n (never stored)

    hipMemsetAsync(deg, 0, NN * 4, stream);
    hipMemsetAsync(stats, 0, 768 * 4, stream);

    // conversions (independent)
    cvt_y_k<<<(NN * 64 / 4 + 255) / 256, 256, 0, stream>>>(y, ybf, NN * 64 / 4);
    cvt_wt_k<<<(128 * 64 + 255) / 256, 256, 0, stream>>>(W1, w1t, 64, 128);
    cvt_wt_k<<<(256 * 128 + 255) / 256, 256, 0, stream>>>(W2, w2t, 128, 256);

    // CSR build (by dst)
    hist_k<<<(NE + 255) / 256, 256, 0, stream>>>(edst, deg, NE);
    scanA_k<<<NBLK_SCAN, 256, 0, stream>>>(deg, rp, partials, NN);
    scanB_k<<<1, 64, 0, stream>>>(partials, NBLK_SCAN);
    scanC_k<<<(NN + 255) / 256, 256, 0, stream>>>(rp, partials, cursor, NN, NE);
    scatter_k<<<(NE + 255) / 256, 256, 0, stream>>>(esrc, edst, ew, cursor, epack, NE);

    // Layer 1: t1 = spmm(ybf); h1 = relu(t1 @ W1) bf16 + fused BN1 stats
    spmm1_k<<<(NN + 3) / 4, 256, 0, stream>>>(ybf, rp, epack, t1, NN);
    mgemm_k<64, true><<<dim3((NN + 63) / 64, 1), 256, 0, stream>>>(
        t1, w1t, h1, colsum1, colsq1, NN, 128);
    bn_fin_k<128><<<1, 128, 0, stream>>>(colsum1, colsq1, gamma1, beta1, scale1, bias1,
                                         1.0f / NN);

    // Layer 2: a2 = scale1*spmm(h1) + wsum*bias1 (bf16); out = relu(a2 @ W2) + BN2 stats
    spmm2_k<<<(NN + 3) / 4, 256, 0, stream>>>(h1, rp, epack, scale1, bias1, a2, NN);
    mgemm_k<128, false><<<dim3((NN + 63) / 64, 2), 256, 0, stream>>>(
        a2, w2t, out, colsum2, colsq2, NN, 256);
    bn_fin_k<256><<<1, 256, 0, stream>>>(colsum2, colsq2, gamma2, beta2, scale2, bias2,
                                         1.0f / NN);
    norm_out_k<<<2048, 256, 0, stream>>>(out, scale2, bias2, NN * 256 / 4);
}